// Round 1
// baseline (2213.298 us; speedup 1.0000x reference)
//
#include <hip/hip_runtime.h>
#include <stdint.h>

// GRU: B=64, T=1024, I=256, H=256, fp32 in/out, bf16 MFMA compute.
// Phase 0 (k_prep): fragmentize 6 weight mats (Wz,Wr,Wh,Uz,Ur,Uh) fp32->bf16
//   into MFMA B-fragment layout; fold biases (bz+cz, br+cr, bh).
// Phase 1 (k_proj): x_m = X@W_m + b'_m for all (t,b), MFMA, one block per t
//   (GEMM rows ordered t*64+b so D-fragments match phase-2 lane layout).
//   Output bf16, 8B/lane fragments -> ws.
// Phase 2 (k_rnn): 4 blocks x 512 thr; block g owns batches 16g..16g+15.
//   Uz,Ur B-frags in registers (128 VGPR), Uh in LDS (128KB),
//   h bf16 A-frags double-buffered in LDS, h master fp32 in registers.
//   1024 sequential steps, 1 barrier/step.

typedef float  f32x4 __attribute__((ext_vector_type(4)));
typedef short  s16x8 __attribute__((ext_vector_type(8)));
typedef unsigned short u16;

#define MFMA_BF16(a, b, c) __builtin_amdgcn_mfma_f32_16x16x32_bf16((a), (b), (c), 0, 0, 0)

static __device__ __forceinline__ u16 f2bf(float f) {
  uint32_t u = __float_as_uint(f);
  u += 0x7FFFu + ((u >> 16) & 1u);   // RNE
  return (u16)(u >> 16);
}
static __device__ __forceinline__ float bf2f(u16 h) {
  return __uint_as_float(((uint32_t)h) << 16);
}
static __device__ __forceinline__ float fast_exp2(float x) {
#if __has_builtin(__builtin_amdgcn_exp2f)
  return __builtin_amdgcn_exp2f(x);
#else
  return exp2f(x);
#endif
}
static __device__ __forceinline__ float fast_rcp(float x) {
#if __has_builtin(__builtin_amdgcn_rcpf)
  return __builtin_amdgcn_rcpf(x);
#else
  return 1.0f / x;
#endif
}
static __device__ __forceinline__ float sigmoid_(float x) {
  return fast_rcp(1.0f + fast_exp2(-1.4426950408889634f * x));
}
static __device__ __forceinline__ float tanh_(float x) {
  float ax = fabsf(x);
  float e  = fast_exp2(-2.885390081777927f * ax);   // exp(-2|x|)
  float r  = (1.0f - e) * fast_rcp(1.0f + e);
  return x < 0.0f ? -r : r;
}

// ---- ws layout (bytes) ----
// [0, 786432)            : 6 mats x 8kk x 16n x 64lane x 16B bf16 fragments
// [786432, 789504)       : folded biases, 3 x 256 fp32
// [1MiB, 1MiB + 96MiB)   : x projections bf16, [m][t][g][n][lane] 8B each
#define WS_BIAS_OFF  786432
#define WS_X_OFF     (1u << 20)

// Fragment convention: kappa(l,i) = (l>>4)*8 + i.
// B-frag (mat, kk, n): lane l slot i = M[32kk + kappa(l,i)][16n + (l&15)]
// A-frag (kk): lane l slot i        = A[l&15][32kk + kappa(l,i)]
// C/D: col = lane&15, row = (lane>>4)*4 + reg   [m89]

__global__ __launch_bounds__(256) void k_prep(
    const float* __restrict__ Wz, const float* __restrict__ Wr, const float* __restrict__ Wh,
    const float* __restrict__ Uz, const float* __restrict__ Ur, const float* __restrict__ Uh,
    const float* __restrict__ bz, const float* __restrict__ br, const float* __restrict__ bh,
    const float* __restrict__ cz, const float* __restrict__ cr, const float* __restrict__ ch,
    u16* __restrict__ wfrag, float* __restrict__ wbias)
{
  if (blockIdx.x == 192) {   // bias fold block
    int c = threadIdx.x;
    wbias[c]       = bz[c] + cz[c];
    wbias[256 + c] = br[c] + cr[c];
    wbias[512 + c] = bh[c];
    return;
  }
  int tid = blockIdx.x * 256 + threadIdx.x;      // 0..49151
  int mat = tid >> 13;                           // 6 mats x 8192 threads
  int kk  = (tid >> 10) & 7;
  int n   = (tid >> 6) & 15;
  int l   = tid & 63;
  const float* M = (mat == 0) ? Wz : (mat == 1) ? Wr : (mat == 2) ? Wh
                 : (mat == 3) ? Uz : (mat == 4) ? Ur : Uh;
  int col   = n * 16 + (l & 15);
  int kbase = kk * 32 + (l >> 4) * 8;
  uint32_t d[4];
#pragma unroll
  for (int p = 0; p < 4; ++p) {
    u16 lo = f2bf(M[(kbase + 2 * p    ) * 256 + col]);
    u16 hi = f2bf(M[(kbase + 2 * p + 1) * 256 + col]);
    d[p] = (uint32_t)lo | ((uint32_t)hi << 16);
  }
  uint32_t* dst = (uint32_t*)(wfrag + ((size_t)mat * 65536 + (size_t)((kk * 16 + n) * 64 + l) * 8));
  dst[0] = d[0]; dst[1] = d[1]; dst[2] = d[2]; dst[3] = d[3];
}

__global__ __launch_bounds__(256) void k_proj(
    const float* __restrict__ X, const u16* __restrict__ wfrag,
    const float* __restrict__ wbias, u16* __restrict__ xout)
{
  __shared__ float As[64 * 256];   // 64KB, XOR-swizzled rows
  const int t   = blockIdx.x;
  const int tid = threadIdx.x;
  const int l   = tid & 63;
  const int w   = tid >> 6;        // wave 0..3 = batch group

  // stage X_t: A[row=b][k=i], row stride 1024B, swizzle byte ^= (row&7)<<4
#pragma unroll
  for (int c = 0; c < 16; ++c) {
    int chunk = c * 256 + tid;       // 0..4095
    int row   = chunk >> 6;
    int q     = (chunk & 63) * 16;
    const char* src = (const char*)X + ((size_t)(row * 1024 + t) * 256) * 4 + q;
    f32x4 v = *(const f32x4*)src;
    *(f32x4*)((char*)As + row * 1024 + (q ^ ((row & 7) << 4))) = v;
  }
  __syncthreads();

  f32x4 acc[3][16];
#pragma unroll
  for (int m = 0; m < 3; ++m)
#pragma unroll
    for (int n = 0; n < 16; ++n) acc[m][n] = 0.0f;

  const s16x8* WB = (const s16x8*)wfrag;
  const int row  = w * 16 + (l & 15);
  const char* arow = (const char*)As + row * 1024;
  const int swz  = (row & 7) << 4;

#pragma unroll
  for (int kk = 0; kk < 8; ++kk) {
    int off = kk * 128 + (l >> 4) * 32;
    f32x4 a0 = *(const f32x4*)(arow + ((off     ) ^ swz));
    f32x4 a1 = *(const f32x4*)(arow + ((off + 16) ^ swz));
    s16x8 af;
    af[0] = (short)f2bf(a0[0]); af[1] = (short)f2bf(a0[1]);
    af[2] = (short)f2bf(a0[2]); af[3] = (short)f2bf(a0[3]);
    af[4] = (short)f2bf(a1[0]); af[5] = (short)f2bf(a1[1]);
    af[6] = (short)f2bf(a1[2]); af[7] = (short)f2bf(a1[3]);
#pragma unroll
    for (int m = 0; m < 3; ++m) {
#pragma unroll
      for (int n = 0; n < 16; ++n) {
        s16x8 bf = WB[(size_t)m * 8192 + (kk * 16 + n) * 64 + l];
        acc[m][n] = MFMA_BF16(af, bf, acc[m][n]);
      }
    }
  }

  const int g = w;
#pragma unroll
  for (int m = 0; m < 3; ++m) {
#pragma unroll
    for (int n = 0; n < 16; ++n) {
      int col = n * 16 + (l & 15);
      float b = wbias[m * 256 + col];
      uint32_t w0 = (uint32_t)f2bf(acc[m][n][0] + b) | ((uint32_t)f2bf(acc[m][n][1] + b) << 16);
      uint32_t w1 = (uint32_t)f2bf(acc[m][n][2] + b) | ((uint32_t)f2bf(acc[m][n][3] + b) << 16);
      size_t idx = ((((size_t)m * 1024 + t) * 4 + g) * 16 + n) * 64 + l;
      ((uint64_t*)xout)[idx] = (uint64_t)w0 | ((uint64_t)w1 << 32);
    }
  }
}

__global__ __launch_bounds__(512) void k_rnn(
    const u16* __restrict__ wfrag, const u16* __restrict__ xin,
    const float* __restrict__ h0, const float* __restrict__ ch,
    float* __restrict__ out)
{
  __shared__ __align__(16) u16 UhF[8 * 16 * 64 * 8];  // 128 KiB Uh fragments
  __shared__ __align__(16) u16 hb[2][4096];           // 2 x 8 KiB h A-frags
  const int g   = blockIdx.x;      // batch group: batches 16g..16g+15
  const int tid = threadIdx.x;
  const int l   = tid & 63;
  const int w   = tid >> 6;        // wave 0..7 owns cols [32w, 32w+32)

  const s16x8* WB = (const s16x8*)wfrag;

  // Uz, Ur register fragments: [n2][kk]
  s16x8 BZ[2][8], BR[2][8];
#pragma unroll
  for (int n2 = 0; n2 < 2; ++n2) {
    int n = w * 2 + n2;
#pragma unroll
    for (int kk = 0; kk < 8; ++kk) {
      BZ[n2][kk] = WB[(size_t)3 * 8192 + (kk * 16 + n) * 64 + l];
      BR[n2][kk] = WB[(size_t)4 * 8192 + (kk * 16 + n) * 64 + l];
    }
  }
  // Uh -> LDS (same fragment layout)
  s16x8* UhV = (s16x8*)UhF;
#pragma unroll
  for (int c = 0; c < 16; ++c) {
    int idx = c * 512 + tid;
    UhV[idx] = WB[(size_t)5 * 8192 + idx];
  }

  // h0 (fp32 master in regs, D-frag layout) + ch
  float hp[2][4];
  float chv[2];
#pragma unroll
  for (int n2 = 0; n2 < 2; ++n2) {
    int col = w * 32 + n2 * 16 + (l & 15);
    chv[n2] = ch[col];
#pragma unroll
    for (int j = 0; j < 4; ++j) {
      int b = g * 16 + (l >> 4) * 4 + j;
      hp[n2][j] = h0[b * 256 + col];
    }
  }
  // seed hb[0]: value (rr,c) -> hb[(c>>5)*512 + (rr + 16*((c>>3)&3))*8 + (c&7)]
#pragma unroll
  for (int n2 = 0; n2 < 2; ++n2) {
    int cb = (2 * n2 + ((l >> 3) & 1)) & 3;   // (c>>3)&3 ; c>>5 == w here
#pragma unroll
    for (int j = 0; j < 4; ++j) {
      int rr = (l >> 4) * 4 + j;
      hb[0][w * 512 + (rr + 16 * cb) * 8 + (l & 7)] = f2bf(hp[n2][j]);
    }
  }
  __syncthreads();

  for (int t = 0; t < 1024; ++t) {
    const int cur = t & 1, nxt = cur ^ 1;

    // x loads, issued early (hidden under MFMAs)
    uint64_t xv[3][2];
#pragma unroll
    for (int m = 0; m < 3; ++m)
#pragma unroll
      for (int n2 = 0; n2 < 2; ++n2) {
        size_t idx = ((((size_t)m * 1024 + t) * 4 + g) * 16 + (w * 2 + n2)) * 64 + l;
        xv[m][n2] = ((const uint64_t*)xin)[idx];
      }

    f32x4 az[2], arr[2], ah[2];
#pragma unroll
    for (int n2 = 0; n2 < 2; ++n2) { az[n2] = 0.0f; arr[n2] = 0.0f; ah[n2] = 0.0f; }

#pragma unroll
    for (int kk = 0; kk < 8; ++kk) {
      s16x8 af = *(const s16x8*)&hb[cur][kk * 512 + l * 8];
#pragma unroll
      for (int n2 = 0; n2 < 2; ++n2) {
        int n = w * 2 + n2;
        s16x8 uh = *(const s16x8*)&UhF[(size_t)((kk * 16 + n) * 64 + l) * 8];
        az[n2]  = MFMA_BF16(af, BZ[n2][kk], az[n2]);
        arr[n2] = MFMA_BF16(af, BR[n2][kk], arr[n2]);
        ah[n2]  = MFMA_BF16(af, uh, ah[n2]);
      }
    }

    // gates, state update, output store, next A-frag write
#pragma unroll
    for (int n2 = 0; n2 < 2; ++n2) {
      int col = w * 32 + n2 * 16 + (l & 15);
      int cb  = (2 * n2 + ((l >> 3) & 1)) & 3;
#pragma unroll
      for (int j = 0; j < 4; ++j) {
        float xz = bf2f((u16)(xv[0][n2] >> (16 * j)));
        float xr = bf2f((u16)(xv[1][n2] >> (16 * j)));
        float xh = bf2f((u16)(xv[2][n2] >> (16 * j)));
        float z  = sigmoid_(xz + az[n2][j]);          // cz folded into xz
        float r  = sigmoid_(xr + arr[n2][j]);         // cr folded into xr
        float hh = tanh_(xh + r * (ah[n2][j] + chv[n2]));
        float hn = z * hp[n2][j] + (1.0f - z) * hh;
        hp[n2][j] = hn;
        int b = g * 16 + (l >> 4) * 4 + j;
        out[((size_t)b * 1024 + t) * 256 + col] = hn;
        int rr = (l >> 4) * 4 + j;
        hb[nxt][w * 512 + (rr + 16 * cb) * 8 + (l & 7)] = f2bf(hn);
      }
    }
    __syncthreads();
  }

  // h_last
#pragma unroll
  for (int n2 = 0; n2 < 2; ++n2) {
    int col = w * 32 + n2 * 16 + (l & 15);
#pragma unroll
    for (int j = 0; j < 4; ++j) {
      int b = g * 16 + (l >> 4) * 4 + j;
      out[(size_t)64 * 1024 * 256 + (size_t)b * 256 + col] = hp[n2][j];
    }
  }
}

extern "C" void kernel_launch(void* const* d_in, const int* in_sizes, int n_in,
                              void* d_out, int out_size, void* d_ws, size_t ws_size,
                              hipStream_t stream) {
  const float* X  = (const float*)d_in[0];
  const float* h0 = (const float*)d_in[1];
  const float* Wz = (const float*)d_in[2];
  const float* Wr = (const float*)d_in[3];
  const float* Wh = (const float*)d_in[4];
  const float* bz = (const float*)d_in[5];
  const float* br = (const float*)d_in[6];
  const float* bh = (const float*)d_in[7];
  const float* Uz = (const float*)d_in[8];
  const float* Ur = (const float*)d_in[9];
  const float* Uh = (const float*)d_in[10];
  const float* cz = (const float*)d_in[11];
  const float* cr = (const float*)d_in[12];
  const float* ch = (const float*)d_in[13];

  char*  ws    = (char*)d_ws;
  u16*   wfrag = (u16*)ws;
  float* wbias = (float*)(ws + WS_BIAS_OFF);
  u16*   xbuf  = (u16*)(ws + WS_X_OFF);
  float* out   = (float*)d_out;

  k_prep<<<193, 256, 0, stream>>>(Wz, Wr, Wh, Uz, Ur, Uh, bz, br, bh, cz, cr, ch,
                                  wfrag, wbias);
  k_proj<<<1024, 256, 0, stream>>>(X, wfrag, wbias, xbuf);
  k_rnn<<<4, 512, 0, stream>>>(wfrag, xbuf, h0, ch, out);
}